// Round 6
// baseline (624.718 us; speedup 1.0000x reference)
//
#include <hip/hip_runtime.h>
#include <hip/hip_bf16.h>

#define B_ 8
#define N_ 4096
#define K_ 16
#define C_ 64
#define NK_ (N_*K_)            // 65536
#define M_ (B_*N_*K_)          // 524288
#define BN_EPS_ 0.001f
#define Q_ (B_*N_)             // 32768 queries
#define NB1_ (M_/128)          // 4096 blocks in layer/stats kernels
#define CAP_ 48                // per-chunk candidate cap (E=16, sigma~5.4, 48 ~ +5.9 sigma)

typedef short bf16x8 __attribute__((ext_vector_type(8)));   // 8 bf16 = 4 VGPRs
typedef float f32x4 __attribute__((ext_vector_type(4)));

// packed f32x2 -> bf16x2 (RNE) via hardware cvt
static __device__ __forceinline__ unsigned pk2bf(float a, float b) {
  union { __hip_bfloat162 h; unsigned u; } c;
  c.h = __float22bfloat162_rn(make_float2(a, b));
  return c.u;
}
static __device__ __forceinline__ unsigned short f2bf1(float x) {
  union { __hip_bfloat16 h; unsigned short u; } c;
  c.h = __float2bfloat16(x);
  return c.u;
}

// TRUE squared distance, rounded exactly like the JAX reference:
// d = (dx*dx + dy*dy) + dz*dz with rn ops. IDENTICAL formula in all knn passes.
// (Round-5 lesson: the expanded key |p2|^2-2p1.p2 is order-equivalent in exact
// arithmetic but its fp32 rounding error flips boundary pairs vs the reference.)
static __device__ __forceinline__ float knn_key(float ax, float ay, float az, float4 c) {
  float dx = ax - c.x, dy = ay - c.y, dz = az - c.z;
  return __fadd_rn(__fadd_rn(__fmul_rn(dx, dx), __fmul_rn(dy, dy)), __fmul_rn(dz, dz));
}

// ---------------- pack points (B,3,N) -> float4 (B*N) ----------------
__global__ __launch_bounds__(256) void pack_pts(const float* __restrict__ p,
                                                float4* __restrict__ pf4) {
  int i = blockIdx.x * 256 + threadIdx.x;
  int b = i >> 12;
  int n = i & (N_ - 1);
  const float* base = p + (size_t)b * 3 * N_;
  pf4[i] = make_float4(base[n], base[N_ + n], base[2 * N_ + n], 0.f);
}

// ---------------- W (128x128 fp32) -> bf16 same layout ----------------
__global__ __launch_bounds__(256) void wcvt(const float* __restrict__ W,
                                            unsigned short* __restrict__ Wb) {
  int i = blockIdx.x * 256 + threadIdx.x;   // 16384
  Wb[i] = f2bf1(W[i]);
}

// ---------------- w0at[d][o] = W0[o][d], d<3 ----------------
__global__ void make_w0at(const float* __restrict__ W0, float* __restrict__ w0at) {
  int o = threadIdx.x;  // 128
  for (int d = 0; d < 3; ++d) w0at[d * 128 + o] = W0[o * 131 + d];
}

// ---------------- zero the 3x256 stats buffer (atomic targets) ----------------
__global__ void zero_stats(float* __restrict__ stats) {
  int i = blockIdx.x * 256 + threadIdx.x;   // 768
  stats[i] = 0.f;
}

// ================= KNN: sampled-threshold exact top-16 =================
// Pass 1: per-lane top-16 keys over 4 sub-chunks of 128 (first 512 candidates).
__global__ __launch_bounds__(64) void knn_sub(const float4* __restrict__ p1f4,
                                              const float4* __restrict__ p2f4,
                                              float* __restrict__ pvals) {
  int lane = threadIdx.x;
  int blk = blockIdx.x;            // c fastest: b(8) x grp(64) x c(4)
  int c = blk & 3;
  int grp = (blk >> 2) & 63;
  int b = blk >> 8;
  int q = (b << 12) + (grp << 6) + lane;
  float4 qv = p1f4[q];
  float ax = qv.x, ay = qv.y, az = qv.z;
  const float4* pb = p2f4 + ((size_t)b << 12) + c * 128;

  float s[16];
  #pragma unroll
  for (int i = 0; i < 16; ++i) s[i] = 3.0e38f;   // desc sorted; s[0]=16th smallest

  #pragma unroll 8
  for (int t = 0; t < 128; ++t) {
    float d = knn_key(ax, ay, az, pb[t]);
    #pragma unroll
    for (int i = 0; i < 15; ++i) s[i] = __builtin_amdgcn_fmed3f(s[i], s[i + 1], d);
    s[15] = fminf(s[15], d);
  }
  #pragma unroll
  for (int i = 0; i < 16; ++i) pvals[(size_t)(c * 16 + i) * Q_ + q] = s[i];
}

// Pass 2: T0[q] = 16th smallest of the 64 per-chunk survivors (== 16th of first 512).
__global__ __launch_bounds__(256) void knn_t0(const float* __restrict__ pvals,
                                              float* __restrict__ Tarr) {
  int q = blockIdx.x * 256 + threadIdx.x;
  float s[16];
  #pragma unroll
  for (int i = 0; i < 16; ++i) s[i] = 3.0e38f;
  #pragma unroll 8
  for (int t = 0; t < 64; ++t) {
    float d = pvals[(size_t)t * Q_ + q];
    #pragma unroll
    for (int i = 0; i < 15; ++i) s[i] = __builtin_amdgcn_fmed3f(s[i], s[i + 1], d);
    s[15] = fminf(s[15], d);
  }
  Tarr[q] = s[0];
}

// Pass 3: collect all candidates with key <= T0 (superset of true top-16), with indices.
__global__ __launch_bounds__(64) void knn_collect(const float4* __restrict__ p1f4,
                                                  const float4* __restrict__ p2f4,
                                                  const float* __restrict__ Tarr,
                                                  uint2* __restrict__ cbuf,
                                                  int* __restrict__ ccnt) {
  int lane = threadIdx.x;
  int blk = blockIdx.x;            // c fastest: b(8) x grp(64) x c(8)
  int c = blk & 7;
  int grp = (blk >> 3) & 63;
  int b = blk >> 9;
  int q = (b << 12) + (grp << 6) + lane;
  float4 qv = p1f4[q];
  float ax = qv.x, ay = qv.y, az = qv.z;
  const float4* pb = p2f4 + ((size_t)b << 12) + c * 512;
  float T = Tarr[q];
  int cnt = 0;
  #pragma unroll 4
  for (int t = 0; t < 512; ++t) {
    float d = knn_key(ax, ay, az, pb[t]);
    if (d <= T && cnt < CAP_) {
      cbuf[(size_t)(c * CAP_ + cnt) * Q_ + q] = make_uint2(__float_as_uint(d), c * 512 + t);
      ++cnt;
    }
  }
  ccnt[c * Q_ + q] = cnt;
}

// Pass 4: exact top-16 over the collected ~128 pairs; emit indices in index order.
__global__ __launch_bounds__(256) void knn_final(const uint2* __restrict__ cbuf,
                                                 const int* __restrict__ ccnt,
                                                 int* __restrict__ idxout) {
  int q = blockIdx.x * 256 + threadIdx.x;
  float s[16];
  #pragma unroll
  for (int i = 0; i < 16; ++i) s[i] = 3.0e38f;
  int cn[8];
  #pragma unroll
  for (int c = 0; c < 8; ++c) {
    int m = ccnt[c * Q_ + q];
    cn[c] = m;
    for (int i = 0; i < m; ++i) {
      float d = __uint_as_float(cbuf[(size_t)(c * CAP_ + i) * Q_ + q].x);
      #pragma unroll
      for (int k = 0; k < 15; ++k) s[k] = __builtin_amdgcn_fmed3f(s[k], s[k + 1], d);
      s[15] = fminf(s[15], d);
    }
  }
  float T = s[0];    // exact 16th smallest
  int tot = 0, ob = q * 16;
  #pragma unroll
  for (int c = 0; c < 8; ++c) {
    int m = cn[c];
    for (int i = 0; i < m && tot < 16; ++i) {
      uint2 e = cbuf[(size_t)(c * CAP_ + i) * Q_ + q];
      if (__uint_as_float(e.x) <= T) idxout[ob + tot++] = (int)e.y;
    }
  }
}

// ---------------- P[bn][o] = sum_c W0[o][coff+c] * f[b][c][n] (+bias) + sgn*w0a[o].pt[bn] ----
__global__ __launch_bounds__(256) void pkern(const float* __restrict__ f,
                                             const float* __restrict__ W0,
                                             const float* __restrict__ bias,
                                             const float4* __restrict__ pf4,
                                             const float* __restrict__ w0at,
                                             float sgn,
                                             float* __restrict__ P, int coff) {
  __shared__ float fx[32 * 65];
  __shared__ __align__(16) float Wl[64 * 132];
  int tid = threadIdx.x;
  int bn0 = blockIdx.x * 32;
  int b = bn0 >> 12, nb0 = bn0 & (N_ - 1);

  for (int u = tid; u < 32 * 64; u += 256) {
    int c = u >> 5, nl = u & 31;
    fx[nl * 65 + c] = f[((size_t)b * C_ + c) * N_ + nb0 + nl];
  }
  for (int u = tid; u < 128 * 64; u += 256) {
    int o = u >> 6, c = u & 63;
    Wl[c * 132 + o] = W0[o * 131 + coff + c];
  }
  __syncthreads();

  int og = tid & 15, np_ = tid >> 4;
  int o0 = og * 8;
  int na = np_ * 2, nb = na + 1;
  float acc0[8], acc1[8];
  #pragma unroll
  for (int j = 0; j < 8; ++j) {
    float bv = bias ? bias[o0 + j] : 0.f;
    acc0[j] = bv; acc1[j] = bv;
  }
  for (int c = 0; c < 64; ++c) {
    float x0 = fx[na * 65 + c], x1 = fx[nb * 65 + c];
    float4 wa = *(const float4*)&Wl[c * 132 + o0];
    float4 wb = *(const float4*)&Wl[c * 132 + o0 + 4];
    float w[8] = {wa.x, wa.y, wa.z, wa.w, wb.x, wb.y, wb.z, wb.w};
    #pragma unroll
    for (int j = 0; j < 8; ++j) {
      acc0[j] = fmaf(x0, w[j], acc0[j]);
      acc1[j] = fmaf(x1, w[j], acc1[j]);
    }
  }
  float4 pa = pf4[bn0 + na], pb_ = pf4[bn0 + nb];
  #pragma unroll
  for (int j = 0; j < 8; ++j) {
    float wx = w0at[o0 + j], wy = w0at[128 + o0 + j], wz = w0at[256 + o0 + j];
    acc0[j] += sgn * (wx * pa.x + wy * pa.y + wz * pa.z);
    acc1[j] += sgn * (wx * pb_.x + wy * pb_.y + wz * pb_.z);
  }
  float* Pa = P + (size_t)(bn0 + na) * 128 + o0;
  float* Pb = P + (size_t)(bn0 + nb) * 128 + o0;
  *(float4*)Pa = make_float4(acc0[0], acc0[1], acc0[2], acc0[3]);
  *(float4*)(Pa + 4) = make_float4(acc0[4], acc0[5], acc0[6], acc0[7]);
  *(float4*)Pb = make_float4(acc1[0], acc1[1], acc1[2], acc1[3]);
  *(float4*)(Pb + 4) = make_float4(acc1[4], acc1[5], acc1[6], acc1[7]);
}

// ---------------- gather ONCE: x0b = bf16(A[n] + Bv[j]); BN0 partials on rounded values ----
__global__ __launch_bounds__(256) void gstats_kernel(
    const float* __restrict__ A, const float* __restrict__ Bv,
    const int* __restrict__ idx, unsigned short* __restrict__ x0b,
    float* __restrict__ part) {
  __shared__ float sred[4 * 128 * 2];
  int tid = threadIdx.x;
  int R0 = blockIdx.x * 128;
  int b = R0 >> 16;
  int n0 = (R0 & (NK_ - 1)) >> 4;
  int cc = (tid & 15) * 8;
  int r0l = tid >> 4;

  int jj[8];
  #pragma unroll
  for (int p = 0; p < 8; ++p) jj[p] = idx[R0 + r0l + p * 16];

  float ssum[8], ssq[8];
  #pragma unroll
  for (int u = 0; u < 8; ++u) { ssum[u] = 0.f; ssq[u] = 0.f; }

  #pragma unroll
  for (int p = 0; p < 8; ++p) {
    const float* Ar = A + (size_t)((b << 12) + n0 + p) * 128 + cc;
    const float* Br = Bv + (size_t)((b << 12) + jj[p]) * 128 + cc;
    float av[8], bv[8];
    *(float4*)&av[0] = *(const float4*)Ar;  *(float4*)&av[4] = *(const float4*)(Ar + 4);
    *(float4*)&bv[0] = *(const float4*)Br;  *(float4*)&bv[4] = *(const float4*)(Br + 4);
    unsigned pw[4];
    #pragma unroll
    for (int i = 0; i < 4; ++i)
      pw[i] = pk2bf(av[2 * i] + bv[2 * i], av[2 * i + 1] + bv[2 * i + 1]);
    uint4 pk; pk.x = pw[0]; pk.y = pw[1]; pk.z = pw[2]; pk.w = pw[3];
    *(uint4*)(x0b + (size_t)(R0 + r0l + p * 16) * 128 + cc) = pk;
    #pragma unroll
    for (int i = 0; i < 4; ++i) {
      float q0 = __uint_as_float(pw[i] << 16);
      float q1 = __uint_as_float(pw[i] & 0xFFFF0000u);
      ssum[2 * i] += q0;     ssq[2 * i] = fmaf(q0, q0, ssq[2 * i]);
      ssum[2 * i + 1] += q1; ssq[2 * i + 1] = fmaf(q1, q1, ssq[2 * i + 1]);
    }
  }
  int w = tid >> 6, lane = tid & 63;
  #pragma unroll
  for (int u = 0; u < 8; ++u) {
    ssum[u] += __shfl_xor(ssum[u], 16);
    ssum[u] += __shfl_xor(ssum[u], 32);
    ssq[u] += __shfl_xor(ssq[u], 16);
    ssq[u] += __shfl_xor(ssq[u], 32);
  }
  if (lane < 16) {
    #pragma unroll
    for (int u = 0; u < 8; ++u) {
      sred[(w * 128 + lane * 8 + u) * 2] = ssum[u];
      sred[(w * 128 + lane * 8 + u) * 2 + 1] = ssq[u];
    }
  }
  __syncthreads();
  if (tid < 128) {
    float a = 0.f, q2 = 0.f;
    #pragma unroll
    for (int ww = 0; ww < 4; ++ww) {
      a += sred[(ww * 128 + tid) * 2];
      q2 += sred[(ww * 128 + tid) * 2 + 1];
    }
    part[(size_t)blockIdx.x * 256 + tid] = a;
    part[(size_t)blockIdx.x * 256 + 128 + tid] = q2;
  }
}

// ---------------- reduce partials: coalesced rows + atomic finish ----------------
__global__ __launch_bounds__(256) void reduce_atomic(const float* __restrict__ part,
                                                     float* __restrict__ statso) {
  int tid = threadIdx.x;
  int r0 = blockIdx.x * 16;
  float a = 0.f;
  #pragma unroll
  for (int i = 0; i < 16; ++i) a += part[(size_t)(r0 + i) * 256 + tid];
  atomicAdd(statso + tid, a);
}

// ---------------- BN finalize ----------------
__global__ void bnfin_kernel(const float* __restrict__ stats, const float* __restrict__ gamma,
                             const float* __restrict__ beta, float* __restrict__ bnp) {
  int o = threadIdx.x;
  const float invM = 1.0f / (float)M_;
  float mean = stats[o] * invM;
  float var = stats[128 + o] * invM - mean * mean;
  float s = gamma[o] * rsqrtf(var + BN_EPS_);
  bnp[o] = s;
  bnp[128 + o] = beta[o] - mean * s;
}

// XOR-swizzled byte address into the 128x128 bf16 LDS tile (row stride 256 B).
static __device__ __forceinline__ char* xsa(unsigned short* Xs, int row, int bytecol) {
  return (char*)Xs + row * 256 + (bytecol ^ ((row & 7) << 4));
}

// ---- stage: Xs = bf16(relu(fma(s0, x0b, t0))), linear reads, swizzled LDS writes ----
static __device__ __forceinline__ void stage_lin(
    unsigned short* Xs, const unsigned short* x0b, const float* bnp0,
    int R0, int tid) {
  int cc = (tid & 15) * 8;
  int r0l = tid >> 4;
  float svv[8], tvv[8];
  *(float4*)&svv[0] = *(const float4*)(bnp0 + cc);       *(float4*)&svv[4] = *(const float4*)(bnp0 + cc + 4);
  *(float4*)&tvv[0] = *(const float4*)(bnp0 + 128 + cc); *(float4*)&tvv[4] = *(const float4*)(bnp0 + 132 + cc);
  #pragma unroll
  for (int p = 0; p < 8; ++p) {
    uint4 pv = *(const uint4*)(x0b + (size_t)(R0 + r0l + p * 16) * 128 + cc);
    float xv[8];
    xv[0] = __uint_as_float(pv.x << 16); xv[1] = __uint_as_float(pv.x & 0xFFFF0000u);
    xv[2] = __uint_as_float(pv.y << 16); xv[3] = __uint_as_float(pv.y & 0xFFFF0000u);
    xv[4] = __uint_as_float(pv.z << 16); xv[5] = __uint_as_float(pv.z & 0xFFFF0000u);
    xv[6] = __uint_as_float(pv.w << 16); xv[7] = __uint_as_float(pv.w & 0xFFFF0000u);
    float y[8];
    #pragma unroll
    for (int u = 0; u < 8; ++u) y[u] = fmaxf(fmaf(svv[u], xv[u], tvv[u]), 0.f);
    uint4 pk;
    pk.x = pk2bf(y[0], y[1]); pk.y = pk2bf(y[2], y[3]);
    pk.z = pk2bf(y[4], y[5]); pk.w = pk2bf(y[6], y[7]);
    *(uint4*)xsa(Xs, r0l + p * 16, 16 * (tid & 15)) = pk;
  }
}

// ---------------- pass1: stage -> GEMM W1 (W in regs, col-split waves) -> BN1 partials ----
__global__ __launch_bounds__(256) void pass1_kernel(
    const unsigned short* __restrict__ x0b, const float* __restrict__ bnp0,
    const unsigned short* __restrict__ W1b, const float* __restrict__ b1,
    float* __restrict__ part) {
  __shared__ __align__(16) unsigned short Xs[128 * 128];   // 32 KB
  int tid = threadIdx.x;
  int R0 = blockIdx.x * 128;

  stage_lin(Xs, x0b, bnp0, R0, tid);

  int w = tid >> 6, lane = tid & 63;
  int m16 = lane & 15, qd = lane >> 4;

  bf16x8 bf[2][4];
  #pragma unroll
  for (int nt = 0; nt < 2; ++nt) {
    const unsigned short* wb = W1b + (size_t)(w * 32 + nt * 16 + m16) * 128 + qd * 8;
    #pragma unroll
    for (int q = 0; q < 4; ++q) bf[nt][q] = *(const bf16x8*)(wb + q * 32);
  }
  __syncthreads();

  f32x4 acc[8][2];
  #pragma unroll
  for (int m = 0; m < 8; ++m) {
    acc[m][0] = (f32x4){0.f, 0.f, 0.f, 0.f};
    acc[m][1] = (f32x4){0.f, 0.f, 0.f, 0.f};
  }
  #pragma unroll
  for (int m = 0; m < 8; ++m) {
    bf16x8 a[4];
    #pragma unroll
    for (int q = 0; q < 4; ++q) a[q] = *(const bf16x8*)xsa(Xs, m * 16 + m16, 16 * qd + 64 * q);
    #pragma unroll
    for (int q = 0; q < 4; ++q) {
      acc[m][0] = __builtin_amdgcn_mfma_f32_16x16x32_bf16(a[q], bf[0][q], acc[m][0], 0, 0, 0);
      acc[m][1] = __builtin_amdgcn_mfma_f32_16x16x32_bf16(a[q], bf[1][q], acc[m][1], 0, 0, 0);
    }
  }

  float ssum[2] = {0.f, 0.f}, ssq[2] = {0.f, 0.f};
  #pragma unroll
  for (int nt = 0; nt < 2; ++nt) {
    float bb = b1[w * 32 + nt * 16 + m16];
    #pragma unroll
    for (int m = 0; m < 8; ++m)
      #pragma unroll
      for (int rg = 0; rg < 4; ++rg) {
        float y = acc[m][nt][rg] + bb;
        ssum[nt] += y;
        ssq[nt] = fmaf(y, y, ssq[nt]);
      }
  }
  #pragma unroll
  for (int nt = 0; nt < 2; ++nt) {
    ssum[nt] += __shfl_xor(ssum[nt], 16);
    ssum[nt] += __shfl_xor(ssum[nt], 32);
    ssq[nt] += __shfl_xor(ssq[nt], 16);
    ssq[nt] += __shfl_xor(ssq[nt], 32);
  }
  if (lane < 16) {
    size_t pb = (size_t)blockIdx.x * 256 + w * 32;
    #pragma unroll
    for (int nt = 0; nt < 2; ++nt) {
      part[pb + nt * 16 + lane] = ssum[nt];
      part[pb + 128 + nt * 16 + lane] = ssq[nt];
    }
  }
}

// ---------------- pass2: stage -> GEMM W1 -> BN1+relu -> GEMM W2 -> max/min + partials ----
__global__ __launch_bounds__(256) void pass2_kernel(
    const unsigned short* __restrict__ x0b, const float* __restrict__ bnp0,
    const unsigned short* __restrict__ W1b, const float* __restrict__ b1,
    const float* __restrict__ bnp1, const unsigned short* __restrict__ W2b,
    const float* __restrict__ b2, float* __restrict__ ymaxo,
    float* __restrict__ ymino, float* __restrict__ part) {
  __shared__ __align__(16) unsigned short Xs[128 * 128];
  int tid = threadIdx.x;
  int R0 = blockIdx.x * 128;
  int b = R0 >> 16;
  int n0 = (R0 & (NK_ - 1)) >> 4;

  stage_lin(Xs, x0b, bnp0, R0, tid);

  int w = tid >> 6, lane = tid & 63;
  int m16 = lane & 15, qd = lane >> 4;

  bf16x8 bf[2][4];
  #pragma unroll
  for (int nt = 0; nt < 2; ++nt) {
    const unsigned short* wb = W1b + (size_t)(w * 32 + nt * 16 + m16) * 128 + qd * 8;
    #pragma unroll
    for (int q = 0; q < 4; ++q) bf[nt][q] = *(const bf16x8*)(wb + q * 32);
  }
  __syncthreads();

  f32x4 acc[8][2];
  #pragma unroll
  for (int m = 0; m < 8; ++m) {
    acc[m][0] = (f32x4){0.f, 0.f, 0.f, 0.f};
    acc[m][1] = (f32x4){0.f, 0.f, 0.f, 0.f};
  }
  #pragma unroll
  for (int m = 0; m < 8; ++m) {
    bf16x8 a[4];
    #pragma unroll
    for (int q = 0; q < 4; ++q) a[q] = *(const bf16x8*)xsa(Xs, m * 16 + m16, 16 * qd + 64 * q);
    #pragma unroll
    for (int q = 0; q < 4; ++q) {
      acc[m][0] = __builtin_amdgcn_mfma_f32_16x16x32_bf16(a[q], bf[0][q], acc[m][0], 0, 0, 0);
      acc[m][1] = __builtin_amdgcn_mfma_f32_16x16x32_bf16(a[q], bf[1][q], acc[m][1], 0, 0, 0);
    }
  }
  __syncthreads();   // all GEMM1 reads of Xs complete

  #pragma unroll
  for (int nt = 0; nt < 2; ++nt) {
    int col = w * 32 + nt * 16 + m16;
    float sc = bnp1[col];
    float tc = fmaf(sc, b1[col], bnp1[128 + col]);
    #pragma unroll
    for (int m = 0; m < 8; ++m)
      #pragma unroll
      for (int rg = 0; rg < 4; ++rg) {
        int row = m * 16 + qd * 4 + rg;
        float y = fmaxf(fmaf(sc, acc[m][nt][rg], tc), 0.f);
        *(unsigned short*)xsa(Xs, row, 2 * col) = f2bf1(y);
      }
  }

  bf16x8 bf2[2][4];
  #pragma unroll
  for (int nt = 0; nt < 2; ++nt) {
    const unsigned short* wb = W2b + (size_t)(w * 32 + nt * 16 + m16) * 128 + qd * 8;
    #pragma unroll
    for (int q = 0; q < 4; ++q) bf2[nt][q] = *(const bf16x8*)(wb + q * 32);
  }
  __syncthreads();   // X1 fully written

  #pragma unroll
  for (int m = 0; m < 8; ++m) {
    acc[m][0] = (f32x4){0.f, 0.f, 0.f, 0.f};
    acc[m][1] = (f32x4){0.f, 0.f, 0.f, 0.f};
  }
  #pragma unroll
  for (int m = 0; m < 8; ++m) {
    bf16x8 a[4];
    #pragma unroll
    for (int q = 0; q < 4; ++q) a[q] = *(const bf16x8*)xsa(Xs, m * 16 + m16, 16 * qd + 64 * q);
    #pragma unroll
    for (int q = 0; q < 4; ++q) {
      acc[m][0] = __builtin_amdgcn_mfma_f32_16x16x32_bf16(a[q], bf2[0][q], acc[m][0], 0, 0, 0);
      acc[m][1] = __builtin_amdgcn_mfma_f32_16x16x32_bf16(a[q], bf2[1][q], acc[m][1], 0, 0, 0);
    }
  }

  float ssum[2] = {0.f, 0.f}, ssq[2] = {0.f, 0.f};
  #pragma unroll
  for (int nt = 0; nt < 2; ++nt) {
    float bb = b2[w * 32 + nt * 16 + m16];
    #pragma unroll
    for (int m = 0; m < 8; ++m) {
      float y0 = acc[m][nt][0] + bb;
      float mx = y0, mn = y0, su = y0, sq = y0 * y0;
      #pragma unroll
      for (int rg = 1; rg < 4; ++rg) {
        float y = acc[m][nt][rg] + bb;
        mx = fmaxf(mx, y); mn = fminf(mn, y);
        su += y; sq = fmaf(y, y, sq);
      }
      mx = fmaxf(mx, __shfl_xor(mx, 16)); mx = fmaxf(mx, __shfl_xor(mx, 32));
      mn = fminf(mn, __shfl_xor(mn, 16)); mn = fminf(mn, __shfl_xor(mn, 32));
      ssum[nt] += su; ssq[nt] += sq;
      if (lane < 16) {
        int n = n0 + m;
        size_t basey = ((size_t)(b << 12) + n) * 128 + w * 32 + nt * 16 + lane;
        ymaxo[basey] = mx;
        ymino[basey] = mn;
      }
    }
  }
  #pragma unroll
  for (int nt = 0; nt < 2; ++nt) {
    ssum[nt] += __shfl_xor(ssum[nt], 16);
    ssum[nt] += __shfl_xor(ssum[nt], 32);
    ssq[nt] += __shfl_xor(ssq[nt], 16);
    ssq[nt] += __shfl_xor(ssq[nt], 32);
  }
  if (lane < 16) {
    size_t pb = (size_t)blockIdx.x * 256 + w * 32;
    #pragma unroll
    for (int nt = 0; nt < 2; ++nt) {
      part[pb + nt * 16 + lane] = ssum[nt];
      part[pb + 128 + nt * 16 + lane] = ssq[nt];
    }
  }
}

// ---------------- final: BN2+relu on max/min, transpose to (B,128,N) ----------------
__global__ __launch_bounds__(256) void final_kernel(const float* __restrict__ ymaxo,
                                                    const float* __restrict__ ymino,
                                                    const float* __restrict__ bnp2,
                                                    float* __restrict__ out) {
  __shared__ float T[64 * 129];
  int tid = threadIdx.x;
  int b = blockIdx.x >> 6;
  int n0 = (blockIdx.x & 63) * 64;
  for (int u = tid; u < 64 * 128; u += 256) {
    int nl = u >> 7, o = u & 127;
    size_t base = ((size_t)(b << 12) + n0 + nl) * 128 + o;
    float s = bnp2[o], t = bnp2[128 + o];
    float v = fmaf(s, (s >= 0.f ? ymaxo[base] : ymino[base]), t);
    T[nl * 129 + o] = fmaxf(v, 0.f);
  }
  __syncthreads();
  for (int u = tid; u < 64 * 128; u += 256) {
    int o = u >> 6, nl = u & 63;
    out[((size_t)b * 128 + o) * N_ + n0 + nl] = T[nl * 129 + o];
  }
}

extern "C" void kernel_launch(void* const* d_in, const int* in_sizes, int n_in,
                              void* d_out, int out_size, void* d_ws, size_t ws_size,
                              hipStream_t stream) {
  (void)in_sizes; (void)n_in; (void)out_size; (void)ws_size;
  const float* points1 = (const float*)d_in[0];
  const float* points2 = (const float*)d_in[1];
  const float* features1 = (const float*)d_in[2];
  const float* features2 = (const float*)d_in[3];
  const float* W0 = (const float*)d_in[4];
  const float* b0 = (const float*)d_in[5];
  const float* g0 = (const float*)d_in[6];
  const float* be0 = (const float*)d_in[7];
  const float* W1 = (const float*)d_in[8];
  const float* b1 = (const float*)d_in[9];
  const float* g1 = (const float*)d_in[10];
  const float* be1 = (const float*)d_in[11];
  const float* W2 = (const float*)d_in[12];
  const float* b2 = (const float*)d_in[13];
  const float* g2 = (const float*)d_in[14];
  const float* be2 = (const float*)d_in[15];
  float* out = (float*)d_out;

  char* ws = (char*)d_ws;
  size_t off = 0;
  auto alloc = [&](size_t bytes) -> void* {
    void* p = ws + off;
    off += (bytes + 255) & ~(size_t)255;
    return p;
  };
  int* idx = (int*)alloc((size_t)M_ * 4);
  float4* p1f4 = (float4*)alloc((size_t)B_ * N_ * 16);
  float4* p2f4 = (float4*)alloc((size_t)B_ * N_ * 16);
  float* A = (float*)alloc((size_t)B_ * N_ * 128 * 4);      // 16 MB
  float* Bv = (float*)alloc((size_t)B_ * N_ * 128 * 4);     // 16 MB
  unsigned short* W1b = (unsigned short*)alloc(128 * 128 * 2);
  unsigned short* W2b = (unsigned short*)alloc(128 * 128 * 2);
  float* w0at = (float*)alloc(3 * 128 * 4);
  float* stats = (float*)alloc(3 * 256 * 4);
  float* bnp = (float*)alloc(3 * 256 * 4);
  float* ymaxo = (float*)alloc((size_t)B_ * N_ * 128 * 4);  // 16 MB
  float* ymino = (float*)alloc((size_t)B_ * N_ * 128 * 4);  // 16 MB
  // 128 MB region: KNN scratch during KNN, then x0b (bf16 x0) for the streamed passes.
  char* bigbuf = (char*)alloc((size_t)128 * 1024 * 1024);
  uint2* cbuf = (uint2*)bigbuf;                                    // 8*CAP_*Q_*8 = 96 MB
  float* pvals = (float*)(bigbuf + (size_t)98 * 1024 * 1024);      // 8 MB
  float* Tarr = (float*)(bigbuf + (size_t)107 * 1024 * 1024);      // 128 KB
  int* ccnt = (int*)(bigbuf + (size_t)108 * 1024 * 1024);          // 1 MB
  unsigned short* x0b = (unsigned short*)bigbuf;                   // 128 MB (after KNN)

  // stats partials aliased onto dead buffers (liveness-checked):
  //  part0 (4 MB, gstats->reduce0) on ymaxo  [ymaxo first written in pass2]
  //  part1 (4 MB, pass1->reduce1)  on ymino  [ymino first written in pass2]
  //  part2 (4 MB, pass2->reduce2)  on A      [A dead after gstats]
  float* part0 = ymaxo;
  float* part1 = ymino;
  float* part2 = A;

  zero_stats<<<3, 256, 0, stream>>>(stats);
  pack_pts<<<B_ * N_ / 256, 256, 0, stream>>>(points1, p1f4);
  pack_pts<<<B_ * N_ / 256, 256, 0, stream>>>(points2, p2f4);
  wcvt<<<64, 256, 0, stream>>>(W1, W1b);
  wcvt<<<64, 256, 0, stream>>>(W2, W2b);
  make_w0at<<<1, 128, 0, stream>>>(W0, w0at);

  knn_sub<<<B_ * 64 * 4, 64, 0, stream>>>(p1f4, p2f4, pvals);
  knn_t0<<<Q_ / 256, 256, 0, stream>>>(pvals, Tarr);
  knn_collect<<<B_ * 64 * 8, 64, 0, stream>>>(p1f4, p2f4, Tarr, cbuf, ccnt);
  knn_final<<<Q_ / 256, 256, 0, stream>>>(cbuf, ccnt, idx);

  pkern<<<B_ * N_ / 32, 256, 0, stream>>>(features1, W0, b0, p1f4, w0at, -1.f, A, 67);
  pkern<<<B_ * N_ / 32, 256, 0, stream>>>(features2, W0, nullptr, p2f4, w0at, 1.f, Bv, 3);

  gstats_kernel<<<NB1_, 256, 0, stream>>>(A, Bv, idx, x0b, part0);
  reduce_atomic<<<NB1_ / 16, 256, 0, stream>>>(part0, stats);
  bnfin_kernel<<<1, 128, 0, stream>>>(stats, g0, be0, bnp);

  pass1_kernel<<<NB1_, 256, 0, stream>>>(x0b, bnp, W1b, b1, part1);
  reduce_atomic<<<NB1_ / 16, 256, 0, stream>>>(part1, stats + 256);
  bnfin_kernel<<<1, 128, 0, stream>>>(stats + 256, g1, be1, bnp + 256);

  pass2_kernel<<<NB1_, 256, 0, stream>>>(x0b, bnp, W1b, b1, bnp + 256,
                                         W2b, b2, ymaxo, ymino, part2);
  reduce_atomic<<<NB1_ / 16, 256, 0, stream>>>(part2, stats + 512);
  bnfin_kernel<<<1, 128, 0, stream>>>(stats + 512, g2, be2, bnp + 512);

  final_kernel<<<B_ * N_ / 64, 256, 0, stream>>>(ymaxo, ymino, bnp + 512, out);
}

// Round 7
// 498.370 us; speedup vs baseline: 1.2535x; 1.2535x over previous
//
#include <hip/hip_runtime.h>
#include <hip/hip_bf16.h>

#define B_ 8
#define N_ 4096
#define K_ 16
#define C_ 64
#define NK_ (N_*K_)            // 65536
#define M_ (B_*N_*K_)          // 524288
#define BN_EPS_ 0.001f
#define Q_ (B_*N_)             // 32768 queries
#define NB1_ (M_/128)          // 4096 blocks in layer/stats kernels
#define CAP_ 48                // per-chunk candidate cap (E=16, sigma~5.4, 48 ~ +5.9 sigma)

typedef short bf16x8 __attribute__((ext_vector_type(8)));   // 8 bf16 = 4 VGPRs
typedef float f32x4 __attribute__((ext_vector_type(4)));

// packed f32x2 -> bf16x2 (RNE) via hardware cvt
static __device__ __forceinline__ unsigned pk2bf(float a, float b) {
  union { __hip_bfloat162 h; unsigned u; } c;
  c.h = __float22bfloat162_rn(make_float2(a, b));
  return c.u;
}
static __device__ __forceinline__ unsigned short f2bf1(float x) {
  union { __hip_bfloat16 h; unsigned short u; } c;
  c.h = __float2bfloat16(x);
  return c.u;
}

// TRUE squared distance, rounded exactly like the JAX reference:
// d = (dx*dx + dy*dy) + dz*dz with rn ops. IDENTICAL formula in all knn passes.
static __device__ __forceinline__ float knn_key(float ax, float ay, float az, float4 c) {
  float dx = ax - c.x, dy = ay - c.y, dz = az - c.z;
  return __fadd_rn(__fadd_rn(__fmul_rn(dx, dx), __fmul_rn(dy, dy)), __fmul_rn(dz, dz));
}

// ---------------- pack points (B,3,N) -> float4 (B*N) ----------------
__global__ __launch_bounds__(256) void pack_pts(const float* __restrict__ p,
                                                float4* __restrict__ pf4) {
  int i = blockIdx.x * 256 + threadIdx.x;
  int b = i >> 12;
  int n = i & (N_ - 1);
  const float* base = p + (size_t)b * 3 * N_;
  pf4[i] = make_float4(base[n], base[N_ + n], base[2 * N_ + n], 0.f);
}

// ---------------- W (128x128 fp32) -> bf16 same layout ----------------
__global__ __launch_bounds__(256) void wcvt(const float* __restrict__ W,
                                            unsigned short* __restrict__ Wb) {
  int i = blockIdx.x * 256 + threadIdx.x;   // 16384
  Wb[i] = f2bf1(W[i]);
}

// ---------------- w0at[d][o] = W0[o][d], d<3 ----------------
__global__ void make_w0at(const float* __restrict__ W0, float* __restrict__ w0at) {
  int o = threadIdx.x;  // 128
  for (int d = 0; d < 3; ++d) w0at[d * 128 + o] = W0[o * 131 + d];
}

// ---------------- zero the 3x256 stats buffer (atomic targets) ----------------
__global__ void zero_stats(float* __restrict__ stats) {
  int i = blockIdx.x * 256 + threadIdx.x;   // 768
  stats[i] = 0.f;
}

// ================= KNN: sampled-threshold exact top-16 =================
// Pass 1: per-lane top-16 keys over 4 sub-chunks of 128 (first 512 candidates).
__global__ __launch_bounds__(64) void knn_sub(const float4* __restrict__ p1f4,
                                              const float4* __restrict__ p2f4,
                                              float* __restrict__ pvals) {
  int lane = threadIdx.x;
  int blk = blockIdx.x;            // c fastest: b(8) x grp(64) x c(4)
  int c = blk & 3;
  int grp = (blk >> 2) & 63;
  int b = blk >> 8;
  int q = (b << 12) + (grp << 6) + lane;
  float4 qv = p1f4[q];
  float ax = qv.x, ay = qv.y, az = qv.z;
  const float4* pb = p2f4 + ((size_t)b << 12) + c * 128;

  float s[16];
  #pragma unroll
  for (int i = 0; i < 16; ++i) s[i] = 3.0e38f;   // desc sorted; s[0]=16th smallest

  #pragma unroll 8
  for (int t = 0; t < 128; ++t) {
    float d = knn_key(ax, ay, az, pb[t]);
    #pragma unroll
    for (int i = 0; i < 15; ++i) s[i] = __builtin_amdgcn_fmed3f(s[i], s[i + 1], d);
    s[15] = fminf(s[15], d);
  }
  #pragma unroll
  for (int i = 0; i < 16; ++i) pvals[(size_t)(c * 16 + i) * Q_ + q] = s[i];
}

// Pass 2: T0[q] = 16th smallest of the 64 per-chunk survivors (== 16th of first 512).
__global__ __launch_bounds__(256) void knn_t0(const float* __restrict__ pvals,
                                              float* __restrict__ Tarr) {
  int q = blockIdx.x * 256 + threadIdx.x;
  float s[16];
  #pragma unroll
  for (int i = 0; i < 16; ++i) s[i] = 3.0e38f;
  #pragma unroll 8
  for (int t = 0; t < 64; ++t) {
    float d = pvals[(size_t)t * Q_ + q];
    #pragma unroll
    for (int i = 0; i < 15; ++i) s[i] = __builtin_amdgcn_fmed3f(s[i], s[i + 1], d);
    s[15] = fminf(s[15], d);
  }
  Tarr[q] = s[0];
}

// Pass 3: collect all candidates with key <= T0 (superset of true top-16), with indices.
// cbuf layout: [q][c][CAP_] -- per-query contiguous so knn_final reads coalesce.
__global__ __launch_bounds__(64) void knn_collect(const float4* __restrict__ p1f4,
                                                  const float4* __restrict__ p2f4,
                                                  const float* __restrict__ Tarr,
                                                  uint2* __restrict__ cbuf,
                                                  int* __restrict__ ccnt) {
  int lane = threadIdx.x;
  int blk = blockIdx.x;            // c fastest: b(8) x grp(64) x c(8)
  int c = blk & 7;
  int grp = (blk >> 3) & 63;
  int b = blk >> 9;
  int q = (b << 12) + (grp << 6) + lane;
  float4 qv = p1f4[q];
  float ax = qv.x, ay = qv.y, az = qv.z;
  const float4* pb = p2f4 + ((size_t)b << 12) + c * 512;
  float T = Tarr[q];
  uint2* cq = cbuf + (size_t)q * (8 * CAP_) + c * CAP_;
  int cnt = 0;
  #pragma unroll 4
  for (int t = 0; t < 512; ++t) {
    float d = knn_key(ax, ay, az, pb[t]);
    if (d <= T && cnt < CAP_) {
      cq[cnt] = make_uint2(__float_as_uint(d), c * 512 + t);
      ++cnt;
    }
  }
  ccnt[c * Q_ + q] = cnt;
}

// Pass 4: one WAVE per query. Lane l holds slot l of each chunk (8 keys/lane).
// Exact 16th-smallest via 16 rounds of wave-min extraction, then ordered
// ballot-compaction (lane order == discovery order == index order).
__global__ __launch_bounds__(256) void knn_final(const uint2* __restrict__ cbuf,
                                                 const int* __restrict__ ccnt,
                                                 int* __restrict__ idxout) {
  int lane = threadIdx.x & 63;
  int q = blockIdx.x * 4 + (threadIdx.x >> 6);
  const uint2* cq = cbuf + (size_t)q * (8 * CAP_);

  float key[8], okey[8];
  unsigned kidx[8];
  #pragma unroll
  for (int c = 0; c < 8; ++c) {
    int m = ccnt[c * Q_ + q];          // wave-uniform -> scalar load
    float k = 3.0e38f; unsigned id = 0;
    if (lane < m) {                    // m <= CAP_ <= 63, no OOB
      uint2 e = cq[c * CAP_ + lane];   // coalesced 384B burst per chunk
      k = __uint_as_float(e.x); id = e.y;
    }
    key[c] = k; okey[c] = k; kidx[c] = id;
  }

  // exact 16th smallest (sum of counts >= 16 guaranteed: true top-16 all <= T0)
  float T = 3.0e38f;
  for (int r = 0; r < 16; ++r) {
    float lm = key[0]; int ls = 0;
    #pragma unroll
    for (int c = 1; c < 8; ++c) if (key[c] < lm) { lm = key[c]; ls = c; }
    float wm = lm;
    wm = fminf(wm, __shfl_xor(wm, 1));
    wm = fminf(wm, __shfl_xor(wm, 2));
    wm = fminf(wm, __shfl_xor(wm, 4));
    wm = fminf(wm, __shfl_xor(wm, 8));
    wm = fminf(wm, __shfl_xor(wm, 16));
    wm = fminf(wm, __shfl_xor(wm, 32));
    T = wm;
    unsigned long long msk = __ballot(lm == wm);
    int owner = __ffsll((long long)msk) - 1;   // remove exactly one instance
    if (lane == owner) key[ls] = 3.0e38f;
  }

  // ordered compaction: take key <= T in (chunk, slot) = index order, cap 16
  int tot = 0, ob = q * 16;
  #pragma unroll
  for (int c = 0; c < 8; ++c) {
    bool take = (okey[c] <= T);
    unsigned long long msk = __ballot(take);
    int pos = tot + __popcll(msk & ((1ull << lane) - 1ull));
    if (take && pos < 16) idxout[ob + pos] = (int)kidx[c];
    tot += __popcll(msk);
  }
}

// ---------------- P[bn][o] = sum_c W0[o][coff+c] * f[b][c][n] (+bias) + sgn*w0a[o].pt[bn] ----
__global__ __launch_bounds__(256) void pkern(const float* __restrict__ f,
                                             const float* __restrict__ W0,
                                             const float* __restrict__ bias,
                                             const float4* __restrict__ pf4,
                                             const float* __restrict__ w0at,
                                             float sgn,
                                             float* __restrict__ P, int coff) {
  __shared__ float fx[32 * 65];
  __shared__ __align__(16) float Wl[64 * 132];
  int tid = threadIdx.x;
  int bn0 = blockIdx.x * 32;
  int b = bn0 >> 12, nb0 = bn0 & (N_ - 1);

  for (int u = tid; u < 32 * 64; u += 256) {
    int c = u >> 5, nl = u & 31;
    fx[nl * 65 + c] = f[((size_t)b * C_ + c) * N_ + nb0 + nl];
  }
  for (int u = tid; u < 128 * 64; u += 256) {
    int o = u >> 6, c = u & 63;
    Wl[c * 132 + o] = W0[o * 131 + coff + c];
  }
  __syncthreads();

  int og = tid & 15, np_ = tid >> 4;
  int o0 = og * 8;
  int na = np_ * 2, nb = na + 1;
  float acc0[8], acc1[8];
  #pragma unroll
  for (int j = 0; j < 8; ++j) {
    float bv = bias ? bias[o0 + j] : 0.f;
    acc0[j] = bv; acc1[j] = bv;
  }
  for (int c = 0; c < 64; ++c) {
    float x0 = fx[na * 65 + c], x1 = fx[nb * 65 + c];
    float4 wa = *(const float4*)&Wl[c * 132 + o0];
    float4 wb = *(const float4*)&Wl[c * 132 + o0 + 4];
    float w[8] = {wa.x, wa.y, wa.z, wa.w, wb.x, wb.y, wb.z, wb.w};
    #pragma unroll
    for (int j = 0; j < 8; ++j) {
      acc0[j] = fmaf(x0, w[j], acc0[j]);
      acc1[j] = fmaf(x1, w[j], acc1[j]);
    }
  }
  float4 pa = pf4[bn0 + na], pb_ = pf4[bn0 + nb];
  #pragma unroll
  for (int j = 0; j < 8; ++j) {
    float wx = w0at[o0 + j], wy = w0at[128 + o0 + j], wz = w0at[256 + o0 + j];
    acc0[j] += sgn * (wx * pa.x + wy * pa.y + wz * pa.z);
    acc1[j] += sgn * (wx * pb_.x + wy * pb_.y + wz * pb_.z);
  }
  float* Pa = P + (size_t)(bn0 + na) * 128 + o0;
  float* Pb = P + (size_t)(bn0 + nb) * 128 + o0;
  *(float4*)Pa = make_float4(acc0[0], acc0[1], acc0[2], acc0[3]);
  *(float4*)(Pa + 4) = make_float4(acc0[4], acc0[5], acc0[6], acc0[7]);
  *(float4*)Pb = make_float4(acc1[0], acc1[1], acc1[2], acc1[3]);
  *(float4*)(Pb + 4) = make_float4(acc1[4], acc1[5], acc1[6], acc1[7]);
}

// ---------------- gather ONCE: x0b = bf16(A[n] + Bv[j]); BN0 partials on rounded values ----
__global__ __launch_bounds__(256) void gstats_kernel(
    const float* __restrict__ A, const float* __restrict__ Bv,
    const int* __restrict__ idx, unsigned short* __restrict__ x0b,
    float* __restrict__ part) {
  __shared__ float sred[4 * 128 * 2];
  int tid = threadIdx.x;
  int R0 = blockIdx.x * 128;
  int b = R0 >> 16;
  int n0 = (R0 & (NK_ - 1)) >> 4;
  int cc = (tid & 15) * 8;
  int r0l = tid >> 4;

  int jj[8];
  #pragma unroll
  for (int p = 0; p < 8; ++p) jj[p] = idx[R0 + r0l + p * 16];

  float ssum[8], ssq[8];
  #pragma unroll
  for (int u = 0; u < 8; ++u) { ssum[u] = 0.f; ssq[u] = 0.f; }

  #pragma unroll
  for (int p = 0; p < 8; ++p) {
    const float* Ar = A + (size_t)((b << 12) + n0 + p) * 128 + cc;
    const float* Br = Bv + (size_t)((b << 12) + jj[p]) * 128 + cc;
    float av[8], bv[8];
    *(float4*)&av[0] = *(const float4*)Ar;  *(float4*)&av[4] = *(const float4*)(Ar + 4);
    *(float4*)&bv[0] = *(const float4*)Br;  *(float4*)&bv[4] = *(const float4*)(Br + 4);
    unsigned pw[4];
    #pragma unroll
    for (int i = 0; i < 4; ++i)
      pw[i] = pk2bf(av[2 * i] + bv[2 * i], av[2 * i + 1] + bv[2 * i + 1]);
    uint4 pk; pk.x = pw[0]; pk.y = pw[1]; pk.z = pw[2]; pk.w = pw[3];
    *(uint4*)(x0b + (size_t)(R0 + r0l + p * 16) * 128 + cc) = pk;
    #pragma unroll
    for (int i = 0; i < 4; ++i) {
      float q0 = __uint_as_float(pw[i] << 16);
      float q1 = __uint_as_float(pw[i] & 0xFFFF0000u);
      ssum[2 * i] += q0;     ssq[2 * i] = fmaf(q0, q0, ssq[2 * i]);
      ssum[2 * i + 1] += q1; ssq[2 * i + 1] = fmaf(q1, q1, ssq[2 * i + 1]);
    }
  }
  int w = tid >> 6, lane = tid & 63;
  #pragma unroll
  for (int u = 0; u < 8; ++u) {
    ssum[u] += __shfl_xor(ssum[u], 16);
    ssum[u] += __shfl_xor(ssum[u], 32);
    ssq[u] += __shfl_xor(ssq[u], 16);
    ssq[u] += __shfl_xor(ssq[u], 32);
  }
  if (lane < 16) {
    #pragma unroll
    for (int u = 0; u < 8; ++u) {
      sred[(w * 128 + lane * 8 + u) * 2] = ssum[u];
      sred[(w * 128 + lane * 8 + u) * 2 + 1] = ssq[u];
    }
  }
  __syncthreads();
  if (tid < 128) {
    float a = 0.f, q2 = 0.f;
    #pragma unroll
    for (int ww = 0; ww < 4; ++ww) {
      a += sred[(ww * 128 + tid) * 2];
      q2 += sred[(ww * 128 + tid) * 2 + 1];
    }
    part[(size_t)blockIdx.x * 256 + tid] = a;
    part[(size_t)blockIdx.x * 256 + 128 + tid] = q2;
  }
}

// ---------------- reduce partials: coalesced rows + atomic finish ----------------
__global__ __launch_bounds__(256) void reduce_atomic(const float* __restrict__ part,
                                                     float* __restrict__ statso) {
  int tid = threadIdx.x;
  int r0 = blockIdx.x * 16;
  float a = 0.f;
  #pragma unroll
  for (int i = 0; i < 16; ++i) a += part[(size_t)(r0 + i) * 256 + tid];
  atomicAdd(statso + tid, a);
}

// ---------------- BN finalize ----------------
__global__ void bnfin_kernel(const float* __restrict__ stats, const float* __restrict__ gamma,
                             const float* __restrict__ beta, float* __restrict__ bnp) {
  int o = threadIdx.x;
  const float invM = 1.0f / (float)M_;
  float mean = stats[o] * invM;
  float var = stats[128 + o] * invM - mean * mean;
  float s = gamma[o] * rsqrtf(var + BN_EPS_);
  bnp[o] = s;
  bnp[128 + o] = beta[o] - mean * s;
}

// XOR-swizzled byte address into the 128x128 bf16 LDS tile (row stride 256 B).
static __device__ __forceinline__ char* xsa(unsigned short* Xs, int row, int bytecol) {
  return (char*)Xs + row * 256 + (bytecol ^ ((row & 7) << 4));
}

// ---- stage: Xs = bf16(relu(fma(s0, x0b, t0))), linear reads, swizzled LDS writes ----
static __device__ __forceinline__ void stage_lin(
    unsigned short* Xs, const unsigned short* x0b, const float* bnp0,
    int R0, int tid) {
  int cc = (tid & 15) * 8;
  int r0l = tid >> 4;
  float svv[8], tvv[8];
  *(float4*)&svv[0] = *(const float4*)(bnp0 + cc);       *(float4*)&svv[4] = *(const float4*)(bnp0 + cc + 4);
  *(float4*)&tvv[0] = *(const float4*)(bnp0 + 128 + cc); *(float4*)&tvv[4] = *(const float4*)(bnp0 + 132 + cc);
  #pragma unroll
  for (int p = 0; p < 8; ++p) {
    uint4 pv = *(const uint4*)(x0b + (size_t)(R0 + r0l + p * 16) * 128 + cc);
    float xv[8];
    xv[0] = __uint_as_float(pv.x << 16); xv[1] = __uint_as_float(pv.x & 0xFFFF0000u);
    xv[2] = __uint_as_float(pv.y << 16); xv[3] = __uint_as_float(pv.y & 0xFFFF0000u);
    xv[4] = __uint_as_float(pv.z << 16); xv[5] = __uint_as_float(pv.z & 0xFFFF0000u);
    xv[6] = __uint_as_float(pv.w << 16); xv[7] = __uint_as_float(pv.w & 0xFFFF0000u);
    float y[8];
    #pragma unroll
    for (int u = 0; u < 8; ++u) y[u] = fmaxf(fmaf(svv[u], xv[u], tvv[u]), 0.f);
    uint4 pk;
    pk.x = pk2bf(y[0], y[1]); pk.y = pk2bf(y[2], y[3]);
    pk.z = pk2bf(y[4], y[5]); pk.w = pk2bf(y[6], y[7]);
    *(uint4*)xsa(Xs, r0l + p * 16, 16 * (tid & 15)) = pk;
  }
}

// ---------------- pass1: stage -> GEMM W1 (W in regs, col-split waves) -> BN1 partials ----
__global__ __launch_bounds__(256) void pass1_kernel(
    const unsigned short* __restrict__ x0b, const float* __restrict__ bnp0,
    const unsigned short* __restrict__ W1b, const float* __restrict__ b1,
    float* __restrict__ part) {
  __shared__ __align__(16) unsigned short Xs[128 * 128];   // 32 KB
  int tid = threadIdx.x;
  int R0 = blockIdx.x * 128;

  stage_lin(Xs, x0b, bnp0, R0, tid);

  int w = tid >> 6, lane = tid & 63;
  int m16 = lane & 15, qd = lane >> 4;

  bf16x8 bf[2][4];
  #pragma unroll
  for (int nt = 0; nt < 2; ++nt) {
    const unsigned short* wb = W1b + (size_t)(w * 32 + nt * 16 + m16) * 128 + qd * 8;
    #pragma unroll
    for (int q = 0; q < 4; ++q) bf[nt][q] = *(const bf16x8*)(wb + q * 32);
  }
  __syncthreads();

  f32x4 acc[8][2];
  #pragma unroll
  for (int m = 0; m < 8; ++m) {
    acc[m][0] = (f32x4){0.f, 0.f, 0.f, 0.f};
    acc[m][1] = (f32x4){0.f, 0.f, 0.f, 0.f};
  }
  #pragma unroll
  for (int m = 0; m < 8; ++m) {
    bf16x8 a[4];
    #pragma unroll
    for (int q = 0; q < 4; ++q) a[q] = *(const bf16x8*)xsa(Xs, m * 16 + m16, 16 * qd + 64 * q);
    #pragma unroll
    for (int q = 0; q < 4; ++q) {
      acc[m][0] = __builtin_amdgcn_mfma_f32_16x16x32_bf16(a[q], bf[0][q], acc[m][0], 0, 0, 0);
      acc[m][1] = __builtin_amdgcn_mfma_f32_16x16x32_bf16(a[q], bf[1][q], acc[m][1], 0, 0, 0);
    }
  }

  float ssum[2] = {0.f, 0.f}, ssq[2] = {0.f, 0.f};
  #pragma unroll
  for (int nt = 0; nt < 2; ++nt) {
    float bb = b1[w * 32 + nt * 16 + m16];
    #pragma unroll
    for (int m = 0; m < 8; ++m)
      #pragma unroll
      for (int rg = 0; rg < 4; ++rg) {
        float y = acc[m][nt][rg] + bb;
        ssum[nt] += y;
        ssq[nt] = fmaf(y, y, ssq[nt]);
      }
  }
  #pragma unroll
  for (int nt = 0; nt < 2; ++nt) {
    ssum[nt] += __shfl_xor(ssum[nt], 16);
    ssum[nt] += __shfl_xor(ssum[nt], 32);
    ssq[nt] += __shfl_xor(ssq[nt], 16);
    ssq[nt] += __shfl_xor(ssq[nt], 32);
  }
  if (lane < 16) {
    size_t pb = (size_t)blockIdx.x * 256 + w * 32;
    #pragma unroll
    for (int nt = 0; nt < 2; ++nt) {
      part[pb + nt * 16 + lane] = ssum[nt];
      part[pb + 128 + nt * 16 + lane] = ssq[nt];
    }
  }
}

// ---------------- pass2: stage -> GEMM W1 -> BN1+relu -> GEMM W2 -> max/min + partials ----
__global__ __launch_bounds__(256) void pass2_kernel(
    const unsigned short* __restrict__ x0b, const float* __restrict__ bnp0,
    const unsigned short* __restrict__ W1b, const float* __restrict__ b1,
    const float* __restrict__ bnp1, const unsigned short* __restrict__ W2b,
    const float* __restrict__ b2, float* __restrict__ ymaxo,
    float* __restrict__ ymino, float* __restrict__ part) {
  __shared__ __align__(16) unsigned short Xs[128 * 128];
  int tid = threadIdx.x;
  int R0 = blockIdx.x * 128;
  int b = R0 >> 16;
  int n0 = (R0 & (NK_ - 1)) >> 4;

  stage_lin(Xs, x0b, bnp0, R0, tid);

  int w = tid >> 6, lane = tid & 63;
  int m16 = lane & 15, qd = lane >> 4;

  bf16x8 bf[2][4];
  #pragma unroll
  for (int nt = 0; nt < 2; ++nt) {
    const unsigned short* wb = W1b + (size_t)(w * 32 + nt * 16 + m16) * 128 + qd * 8;
    #pragma unroll
    for (int q = 0; q < 4; ++q) bf[nt][q] = *(const bf16x8*)(wb + q * 32);
  }
  __syncthreads();

  f32x4 acc[8][2];
  #pragma unroll
  for (int m = 0; m < 8; ++m) {
    acc[m][0] = (f32x4){0.f, 0.f, 0.f, 0.f};
    acc[m][1] = (f32x4){0.f, 0.f, 0.f, 0.f};
  }
  #pragma unroll
  for (int m = 0; m < 8; ++m) {
    bf16x8 a[4];
    #pragma unroll
    for (int q = 0; q < 4; ++q) a[q] = *(const bf16x8*)xsa(Xs, m * 16 + m16, 16 * qd + 64 * q);
    #pragma unroll
    for (int q = 0; q < 4; ++q) {
      acc[m][0] = __builtin_amdgcn_mfma_f32_16x16x32_bf16(a[q], bf[0][q], acc[m][0], 0, 0, 0);
      acc[m][1] = __builtin_amdgcn_mfma_f32_16x16x32_bf16(a[q], bf[1][q], acc[m][1], 0, 0, 0);
    }
  }
  __syncthreads();   // all GEMM1 reads of Xs complete

  #pragma unroll
  for (int nt = 0; nt < 2; ++nt) {
    int col = w * 32 + nt * 16 + m16;
    float sc = bnp1[col];
    float tc = fmaf(sc, b1[col], bnp1[128 + col]);
    #pragma unroll
    for (int m = 0; m < 8; ++m)
      #pragma unroll
      for (int rg = 0; rg < 4; ++rg) {
        int row = m * 16 + qd * 4 + rg;
        float y = fmaxf(fmaf(sc, acc[m][nt][rg], tc), 0.f);
        *(unsigned short*)xsa(Xs, row, 2 * col) = f2bf1(y);
      }
  }

  bf16x8 bf2[2][4];
  #pragma unroll
  for (int nt = 0; nt < 2; ++nt) {
    const unsigned short* wb = W2b + (size_t)(w * 32 + nt * 16 + m16) * 128 + qd * 8;
    #pragma unroll
    for (int q = 0; q < 4; ++q) bf2[nt][q] = *(const bf16x8*)(wb + q * 32);
  }
  __syncthreads();   // X1 fully written

  #pragma unroll
  for (int m = 0; m < 8; ++m) {
    acc[m][0] = (f32x4){0.f, 0.f, 0.f, 0.f};
    acc[m][1] = (f32x4){0.f, 0.f, 0.f, 0.f};
  }
  #pragma unroll
  for (int m = 0; m < 8; ++m) {
    bf16x8 a[4];
    #pragma unroll
    for (int q = 0; q < 4; ++q) a[q] = *(const bf16x8*)xsa(Xs, m * 16 + m16, 16 * qd + 64 * q);
    #pragma unroll
    for (int q = 0; q < 4; ++q) {
      acc[m][0] = __builtin_amdgcn_mfma_f32_16x16x32_bf16(a[q], bf2[0][q], acc[m][0], 0, 0, 0);
      acc[m][1] = __builtin_amdgcn_mfma_f32_16x16x32_bf16(a[q], bf2[1][q], acc[m][1], 0, 0, 0);
    }
  }

  float ssum[2] = {0.f, 0.f}, ssq[2] = {0.f, 0.f};
  #pragma unroll
  for (int nt = 0; nt < 2; ++nt) {
    float bb = b2[w * 32 + nt * 16 + m16];
    #pragma unroll
    for (int m = 0; m < 8; ++m) {
      float y0 = acc[m][nt][0] + bb;
      float mx = y0, mn = y0, su = y0, sq = y0 * y0;
      #pragma unroll
      for (int rg = 1; rg < 4; ++rg) {
        float y = acc[m][nt][rg] + bb;
        mx = fmaxf(mx, y); mn = fminf(mn, y);
        su += y; sq = fmaf(y, y, sq);
      }
      mx = fmaxf(mx, __shfl_xor(mx, 16)); mx = fmaxf(mx, __shfl_xor(mx, 32));
      mn = fminf(mn, __shfl_xor(mn, 16)); mn = fminf(mn, __shfl_xor(mn, 32));
      ssum[nt] += su; ssq[nt] += sq;
      if (lane < 16) {
        int n = n0 + m;
        size_t basey = ((size_t)(b << 12) + n) * 128 + w * 32 + nt * 16 + lane;
        ymaxo[basey] = mx;
        ymino[basey] = mn;
      }
    }
  }
  #pragma unroll
  for (int nt = 0; nt < 2; ++nt) {
    ssum[nt] += __shfl_xor(ssum[nt], 16);
    ssum[nt] += __shfl_xor(ssum[nt], 32);
    ssq[nt] += __shfl_xor(ssq[nt], 16);
    ssq[nt] += __shfl_xor(ssq[nt], 32);
  }
  if (lane < 16) {
    size_t pb = (size_t)blockIdx.x * 256 + w * 32;
    #pragma unroll
    for (int nt = 0; nt < 2; ++nt) {
      part[pb + nt * 16 + lane] = ssum[nt];
      part[pb + 128 + nt * 16 + lane] = ssq[nt];
    }
  }
}

// ---------------- final: BN2+relu on max/min, transpose to (B,128,N) ----------------
__global__ __launch_bounds__(256) void final_kernel(const float* __restrict__ ymaxo,
                                                    const float* __restrict__ ymino,
                                                    const float* __restrict__ bnp2,
                                                    float* __restrict__ out) {
  __shared__ float T[64 * 129];
  int tid = threadIdx.x;
  int b = blockIdx.x >> 6;
  int n0 = (blockIdx.x & 63) * 64;
  for (int u = tid; u < 64 * 128; u += 256) {
    int nl = u >> 7, o = u & 127;
    size_t base = ((size_t)(b << 12) + n0 + nl) * 128 + o;
    float s = bnp2[o], t = bnp2[128 + o];
    float v = fmaf(s, (s >= 0.f ? ymaxo[base] : ymino[base]), t);
    T[nl * 129 + o] = fmaxf(v, 0.f);
  }
  __syncthreads();
  for (int u = tid; u < 64 * 128; u += 256) {
    int o = u >> 6, nl = u & 63;
    out[((size_t)b * 128 + o) * N_ + n0 + nl] = T[nl * 129 + o];
  }
}

extern "C" void kernel_launch(void* const* d_in, const int* in_sizes, int n_in,
                              void* d_out, int out_size, void* d_ws, size_t ws_size,
                              hipStream_t stream) {
  (void)in_sizes; (void)n_in; (void)out_size; (void)ws_size;
  const float* points1 = (const float*)d_in[0];
  const float* points2 = (const float*)d_in[1];
  const float* features1 = (const float*)d_in[2];
  const float* features2 = (const float*)d_in[3];
  const float* W0 = (const float*)d_in[4];
  const float* b0 = (const float*)d_in[5];
  const float* g0 = (const float*)d_in[6];
  const float* be0 = (const float*)d_in[7];
  const float* W1 = (const float*)d_in[8];
  const float* b1 = (const float*)d_in[9];
  const float* g1 = (const float*)d_in[10];
  const float* be1 = (const float*)d_in[11];
  const float* W2 = (const float*)d_in[12];
  const float* b2 = (const float*)d_in[13];
  const float* g2 = (const float*)d_in[14];
  const float* be2 = (const float*)d_in[15];
  float* out = (float*)d_out;

  char* ws = (char*)d_ws;
  size_t off = 0;
  auto alloc = [&](size_t bytes) -> void* {
    void* p = ws + off;
    off += (bytes + 255) & ~(size_t)255;
    return p;
  };
  int* idx = (int*)alloc((size_t)M_ * 4);
  float4* p1f4 = (float4*)alloc((size_t)B_ * N_ * 16);
  float4* p2f4 = (float4*)alloc((size_t)B_ * N_ * 16);
  float* A = (float*)alloc((size_t)B_ * N_ * 128 * 4);      // 16 MB
  float* Bv = (float*)alloc((size_t)B_ * N_ * 128 * 4);     // 16 MB
  unsigned short* W1b = (unsigned short*)alloc(128 * 128 * 2);
  unsigned short* W2b = (unsigned short*)alloc(128 * 128 * 2);
  float* w0at = (float*)alloc(3 * 128 * 4);
  float* stats = (float*)alloc(3 * 256 * 4);
  float* bnp = (float*)alloc(3 * 256 * 4);
  float* ymaxo = (float*)alloc((size_t)B_ * N_ * 128 * 4);  // 16 MB
  float* ymino = (float*)alloc((size_t)B_ * N_ * 128 * 4);  // 16 MB
  // 128 MB region: KNN scratch during KNN, then x0b (bf16 x0) for the streamed passes.
  char* bigbuf = (char*)alloc((size_t)128 * 1024 * 1024);
  uint2* cbuf = (uint2*)bigbuf;                                    // Q_*8*CAP_*8 = 96 MB
  float* pvals = (float*)(bigbuf + (size_t)98 * 1024 * 1024);      // 8 MB
  float* Tarr = (float*)(bigbuf + (size_t)107 * 1024 * 1024);      // 128 KB
  int* ccnt = (int*)(bigbuf + (size_t)108 * 1024 * 1024);          // 1 MB
  unsigned short* x0b = (unsigned short*)bigbuf;                   // 128 MB (after KNN)

  // stats partials aliased onto dead buffers (liveness-checked):
  //  part0 (4 MB, gstats->reduce0) on ymaxo  [ymaxo first written in pass2]
  //  part1 (4 MB, pass1->reduce1)  on ymino  [ymino first written in pass2]
  //  part2 (4 MB, pass2->reduce2)  on A      [A dead after gstats]
  float* part0 = ymaxo;
  float* part1 = ymino;
  float* part2 = A;

  zero_stats<<<3, 256, 0, stream>>>(stats);
  pack_pts<<<B_ * N_ / 256, 256, 0, stream>>>(points1, p1f4);
  pack_pts<<<B_ * N_ / 256, 256, 0, stream>>>(points2, p2f4);
  wcvt<<<64, 256, 0, stream>>>(W1, W1b);
  wcvt<<<64, 256, 0, stream>>>(W2, W2b);
  make_w0at<<<1, 128, 0, stream>>>(W0, w0at);

  knn_sub<<<B_ * 64 * 4, 64, 0, stream>>>(p1f4, p2f4, pvals);
  knn_t0<<<Q_ / 256, 256, 0, stream>>>(pvals, Tarr);
  knn_collect<<<B_ * 64 * 8, 64, 0, stream>>>(p1f4, p2f4, Tarr, cbuf, ccnt);
  knn_final<<<Q_ / 4, 256, 0, stream>>>(cbuf, ccnt, idx);

  pkern<<<B_ * N_ / 32, 256, 0, stream>>>(features1, W0, b0, p1f4, w0at, -1.f, A, 67);
  pkern<<<B_ * N_ / 32, 256, 0, stream>>>(features2, W0, nullptr, p2f4, w0at, 1.f, Bv, 3);

  gstats_kernel<<<NB1_, 256, 0, stream>>>(A, Bv, idx, x0b, part0);
  reduce_atomic<<<NB1_ / 16, 256, 0, stream>>>(part0, stats);
  bnfin_kernel<<<1, 128, 0, stream>>>(stats, g0, be0, bnp);

  pass1_kernel<<<NB1_, 256, 0, stream>>>(x0b, bnp, W1b, b1, part1);
  reduce_atomic<<<NB1_ / 16, 256, 0, stream>>>(part1, stats + 256);
  bnfin_kernel<<<1, 128, 0, stream>>>(stats + 256, g1, be1, bnp + 256);

  pass2_kernel<<<NB1_, 256, 0, stream>>>(x0b, bnp, W1b, b1, bnp + 256,
                                         W2b, b2, ymaxo, ymino, part2);
  reduce_atomic<<<NB1_ / 16, 256, 0, stream>>>(part2, stats + 512);
  bnfin_kernel<<<1, 128, 0, stream>>>(stats + 512, g2, be2, bnp + 512);

  final_kernel<<<B_ * N_ / 64, 256, 0, stream>>>(ymaxo, ymino, bnp + 512, out);
}